// Round 3
// baseline (192.372 us; speedup 1.0000x reference)
//
#include <hip/hip_runtime.h>
#include <hip/hip_fp16.h>

// imgs (8,3,1024,1024) fp32, z (1e6,2) fp32 -> out (8,2) fp32.
// R14 (this round):
//  - precompute: ROWS=2 per block with ALL 18 float4 loads issued upfront
//    (R12's failure was 6-load rolling stages + 1024-block grid; this keeps
//    2048 blocks / 4 blocks/CU and 1.5x the MLP of R11's 12 loads while
//    cutting the raw-row re-read from 2x to 1.5x pre-L2).
//  - stage buffer halved to 8 KB (two 128-column copy-out rounds) so LDS =
//    24.96 + 8.19 = 33.2 KB stays under the 40 KB 4-blocks/CU limit.
//  - XCD swizzle retained (chunk 256, y-major): adjacent y-groups share the
//    boundary row y0+2 in the same XCD's L2.
//  - gather + fused reduce byte-identical to R13 (2-pair unroll, atomicAdd).
// T record per pixel: 64 B = uint4[4]: [0]=Dy(8 half), [1]=Dx, [2]=M,
// [3]=pad -> exactly one cache line per gathered point.

#define NYX 1024
#define NPIX (NYX * NYX)
#define BATCH 8
#define CH 3
#define GB 1024                                  // gather blocks
#define SROW 260                                 // LDS S-row stride (floats)
#define SW(i) ((i) ^ (((i) >> 4) & 7))           // stage swizzle (involution)

__device__ __forceinline__ unsigned pk2(float a, float b) {
    __half2 h = __floats2half2_rn(a, b);
    return *(unsigned*)&h;
}

__device__ __forceinline__ float4 add4(float4 a, float4 b, float4 c) {
    return make_float4(a.x + b.x + c.x, a.y + b.y + c.y,
                       a.z + b.z + c.z, a.w + b.w + c.w);
}

__global__ __launch_bounds__(256, 4) void precompute_kernel(
    const float* __restrict__ imgs, uint4* __restrict__ T,
    float* __restrict__ out)
{
    // 2048 blocks. XCD swizzle: chunk of 256 logical blocks per XCD,
    // logical order y-major within a strip so adjacent y-groups (which share
    // boundary row y0+2) are dispatched back-to-back on the same XCD.
    int bid0  = blockIdx.x;
    int L     = ((bid0 & 7) << 8) | (bid0 >> 3); // bijective on [0,2048)
    int yg    = L & 511;
    int strip = L >> 9;                          // 0..3
    int y0    = yg << 1;
    int x0    = strip << 8;
    int t     = threadIdx.x;
    int lane  = t & 63;
    int g     = t >> 6;                          // group -> batches 2g,2g+1
    int xe    = min(x0 + 256, NYX - 1);          // strip-edge col

    if (bid0 == 0 && t < 16) out[t] = 0.0f;      // zero for gather's atomics

    __shared__ float sS[BATCH * 3 * SROW];       // 24960 B: 3 S-rows x 8 b
    __shared__ uint4 stage[512];                 // 8192 B: 128 records

    int yr0 = y0;
    int yr1 = min(y0 + 1, NYX - 1);
    int yr2 = min(y0 + 2, NYX - 1);              // row 1023 records unread
    size_t q[3] = { (size_t)yr0 * NYX + x0,
                    (size_t)yr1 * NYX + x0,
                    (size_t)yr2 * NYX + x0 };

    // 18 independent float4 loads (3 rows x 2 batches x 3 channels)
    float4 v[18];
#pragma unroll
    for (int r = 0; r < 3; ++r) {
#pragma unroll
        for (int bl = 0; bl < 2; ++bl) {
#pragma unroll
            for (int c = 0; c < CH; ++c) {
                const float* pl = imgs + (size_t)((2 * g + bl) * CH + c) * NPIX;
                v[r * 6 + bl * 3 + c] = ((const float4*)(pl + q[r]))[lane];
            }
        }
    }
    float edge[6] = {0.f, 0.f, 0.f, 0.f, 0.f, 0.f};
    if (lane == 63) {
        size_t qe[3] = { (size_t)yr0 * NYX + xe,
                         (size_t)yr1 * NYX + xe,
                         (size_t)yr2 * NYX + xe };
#pragma unroll
        for (int r = 0; r < 3; ++r) {
#pragma unroll
            for (int bl = 0; bl < 2; ++bl) {
#pragma unroll
                for (int c = 0; c < CH; ++c) {
                    const float* pl = imgs + (size_t)((2 * g + bl) * CH + c) * NPIX;
                    edge[r * 2 + bl] += pl[qe[r]];
                }
            }
        }
    }

    // channel-sum -> 3 S rows per batch
#pragma unroll
    for (int r = 0; r < 3; ++r) {
#pragma unroll
        for (int bl = 0; bl < 2; ++bl) {
            int b = 2 * g + bl;
            float4 s = add4(v[r * 6 + bl * 3 + 0], v[r * 6 + bl * 3 + 1],
                            v[r * 6 + bl * 3 + 2]);
            *(float4*)&sS[(b * 3 + r) * SROW + 4 * lane] = s;
            if (lane == 63) sS[(b * 3 + r) * SROW + 256] = edge[r * 2 + bl];
        }
    }
    __syncthreads();

#pragma unroll
    for (int k = 0; k < 2; ++k) {
        // per-thread record for pixel (y0+k, x0+t) from S rows k, k+1
        float Dy[BATCH], Dx[BATCH], Mm[BATCH];
#pragma unroll
        for (int b = 0; b < BATCH; ++b) {
            float c00 = sS[(b * 3 + k)     * SROW + t];
            float c01 = sS[(b * 3 + k)     * SROW + t + 1];
            float c10 = sS[(b * 3 + k + 1) * SROW + t];
            float c11 = sS[(b * 3 + k + 1) * SROW + t + 1];
            Dy[b] = c10 - c00;
            Dx[b] = c01 - c00;
            Mm[b] = (c11 - c01) - Dy[b];
        }
        size_t base4 = ((size_t)(y0 + k) * NYX + x0) * 4;
        // two 128-column rounds through the 8 KB stage
#pragma unroll
        for (int h = 0; h < 2; ++h) {
            if ((t >> 7) == h) {
                int tt = t & 127;
                stage[SW(tt * 4 + 0)] =
                    make_uint4(pk2(Dy[0], Dy[1]), pk2(Dy[2], Dy[3]),
                               pk2(Dy[4], Dy[5]), pk2(Dy[6], Dy[7]));
                stage[SW(tt * 4 + 1)] =
                    make_uint4(pk2(Dx[0], Dx[1]), pk2(Dx[2], Dx[3]),
                               pk2(Dx[4], Dx[5]), pk2(Dx[6], Dx[7]));
                stage[SW(tt * 4 + 2)] =
                    make_uint4(pk2(Mm[0], Mm[1]), pk2(Mm[2], Mm[3]),
                               pk2(Mm[4], Mm[5]), pk2(Mm[6], Mm[7]));
                stage[SW(tt * 4 + 3)] = make_uint4(0u, 0u, 0u, 0u);
            }
            __syncthreads();
            // coalesced copy-out: 512 consecutive uint4 (8 KB, full lines)
#pragma unroll
            for (int i = 0; i < 2; ++i)
                T[base4 + h * 512 + i * 256 + t] = stage[SW(i * 256 + t)];
            __syncthreads();
        }
    }
}

struct PtSetup {
    const uint4* t4;
    float u, v, s;
};

__device__ __forceinline__ PtSetup setup_pt(float zy, float zx,
                                            const uint4* __restrict__ T) {
    PtSetup r;
    float x0y = zy * (float)(NYX - 1);
    float x0x = zx * (float)(NYX - 1);
    bool oob = (x0y < 0.0f) || (x0y > (float)(NYX - 1)) ||
               (x0x < 0.0f) || (x0x > (float)(NYX - 1));
    float cy = fminf(fmaxf(x0y, 0.0f), (float)(NYX - 1));
    float cx = fminf(fmaxf(x0x, 0.0f), (float)(NYX - 1));
    int yg = min((int)cy, NYX - 2);
    int xg = min((int)cx, NYX - 2);
    r.u = cx - (float)xg;
    r.v = cy - (float)yg;
    r.s = oob ? 0.0f : 1.0f;
    r.t4 = T + ((size_t)yg * NYX + xg) * 4;
    return r;
}

__device__ __forceinline__ void accum_pt(PtSetup P, uint4 rDy, uint4 rDx,
                                         uint4 rM, float* acc0, float* acc1) {
    const __half2* hDy = (const __half2*)&rDy;
    const __half2* hDx = (const __half2*)&rDx;
    const __half2* hM  = (const __half2*)&rM;
#pragma unroll
    for (int j = 0; j < 4; ++j) {
        float2 dy = __half22float2(hDy[j]);
        float2 dx = __half22float2(hDx[j]);
        float2 m  = __half22float2(hM[j]);
        acc0[2 * j + 0] += P.s * fmaf(P.u, m.x, dy.x);
        acc0[2 * j + 1] += P.s * fmaf(P.u, m.y, dy.y);
        acc1[2 * j + 0] += P.s * fmaf(P.v, m.x, dx.x);
        acc1[2 * j + 1] += P.s * fmaf(P.v, m.y, dx.y);
    }
}

__global__ __launch_bounds__(256, 4) void gather_kernel(
    const float* __restrict__ z, const uint4* __restrict__ T,
    float* __restrict__ out, int npts)
{
    float acc0[BATCH];
    float acc1[BATCH];
#pragma unroll
    for (int b = 0; b < BATCH; ++b) { acc0[b] = 0.0f; acc1[b] = 0.0f; }

    const float4* z4 = (const float4*)z;
    int npairs = npts >> 1;
    int stride = gridDim.x * blockDim.x;
    int tid = blockIdx.x * blockDim.x + threadIdx.x;

    // 2 pairs (4 points) per iteration: 2 z-loads + 12 record loads in flight
    for (int i = tid; i < npairs; i += 2 * stride) {
        int i2 = i + stride;
        bool has2 = i2 < npairs;
        float4 za = z4[i];
        float4 zb = z4[has2 ? i2 : i];           // clamped dup, zeroed below
        PtSetup A = setup_pt(za.x, za.y, T);
        PtSetup B = setup_pt(za.z, za.w, T);
        PtSetup C = setup_pt(zb.x, zb.y, T);
        PtSetup D = setup_pt(zb.z, zb.w, T);
        if (!has2) { C.s = 0.0f; D.s = 0.0f; }
        uint4 aDy = A.t4[0], aDx = A.t4[1], aM = A.t4[2];
        uint4 bDy = B.t4[0], bDx = B.t4[1], bM = B.t4[2];
        uint4 cDy = C.t4[0], cDx = C.t4[1], cM = C.t4[2];
        uint4 dDy = D.t4[0], dDx = D.t4[1], dM = D.t4[2];
        accum_pt(A, aDy, aDx, aM, acc0, acc1);
        accum_pt(B, bDy, bDx, bM, acc0, acc1);
        accum_pt(C, cDy, cDx, cM, acc0, acc1);
        accum_pt(D, dDy, dDx, dM, acc0, acc1);
    }

    // odd-npts tail (not taken for npts = 1e6)
    if ((npts & 1) && blockIdx.x == 0 && threadIdx.x == 0) {
        float zy = z[2 * (npts - 1)], zx = z[2 * (npts - 1) + 1];
        PtSetup A = setup_pt(zy, zx, T);
        uint4 aDy = A.t4[0], aDx = A.t4[1], aM = A.t4[2];
        accum_pt(A, aDy, aDx, aM, acc0, acc1);
    }

#pragma unroll
    for (int b = 0; b < BATCH; ++b) {
#pragma unroll
        for (int off = 32; off > 0; off >>= 1) {
            acc0[b] += __shfl_down(acc0[b], off, 64);
            acc1[b] += __shfl_down(acc1[b], off, 64);
        }
    }

    __shared__ float sred[4][16];
    int lane = threadIdx.x & 63;
    int wave = threadIdx.x >> 6;
    if (lane == 0) {
#pragma unroll
        for (int b = 0; b < BATCH; ++b) {
            sred[wave][2 * b + 0] = acc0[b];
            sred[wave][2 * b + 1] = acc1[b];
        }
    }
    __syncthreads();
    if (threadIdx.x < 16) {
        float s = sred[0][threadIdx.x] + sred[1][threadIdx.x] +
                  sred[2][threadIdx.x] + sred[3][threadIdx.x];
        atomicAdd(&out[threadIdx.x], s);         // out zeroed by precompute
    }
}

// ---- fallback (round-1 unsorted path) if ws is too small ----
__global__ void zero_out_kernel(float* __restrict__ out) {
    int i = threadIdx.x;
    if (i < 16) out[i] = 0.0f;
}

__global__ __launch_bounds__(256) void interp_grad_kernel(
    const float* __restrict__ imgs, const float* __restrict__ z,
    float* __restrict__ out, int npts)
{
    int p = blockIdx.x * blockDim.x + threadIdx.x;
    float acc0[BATCH];
    float acc1[BATCH];
#pragma unroll
    for (int b = 0; b < BATCH; ++b) { acc0[b] = 0.0f; acc1[b] = 0.0f; }
    if (p < npts) {
        float2 zz = ((const float2*)z)[p];
        float x0y = zz.x * (float)(NYX - 1);
        float x0x = zz.y * (float)(NYX - 1);
        bool oob = (x0y < 0.0f) || (x0y > (float)(NYX - 1)) ||
                   (x0x < 0.0f) || (x0x > (float)(NYX - 1));
        if (!oob) {
            int yg = min((int)floorf(x0y), NYX - 2);
            int xg = min((int)floorf(x0x), NYX - 2);
            float fy = (float)yg - x0y;
            float fx = (float)xg - x0x;
            const float* base = imgs + (size_t)yg * NYX + xg;
#pragma unroll
            for (int b = 0; b < BATCH; ++b) {
#pragma unroll
                for (int c = 0; c < CH; ++c) {
                    const float* pl = base + (size_t)(b * CH + c) * (size_t)NPIX;
                    float g00 = pl[0];
                    float g01 = pl[1];
                    float g10 = pl[NYX];
                    float g11 = pl[NYX + 1];
                    float a1 = g10 - g00;
                    float a2 = g11 - g01;
                    float a3 = g01 - g00;
                    float d  = a1 - a2;
                    acc0[b] += d * fx + a1;
                    acc1[b] += d * fy + a3;
                }
            }
        }
    }
#pragma unroll
    for (int b = 0; b < BATCH; ++b) {
#pragma unroll
        for (int off = 32; off > 0; off >>= 1) {
            acc0[b] += __shfl_down(acc0[b], off, 64);
            acc1[b] += __shfl_down(acc1[b], off, 64);
        }
    }
    __shared__ float sred[4][16];
    int lane = threadIdx.x & 63;
    int wave = threadIdx.x >> 6;
    if (lane == 0) {
#pragma unroll
        for (int b = 0; b < BATCH; ++b) {
            sred[wave][2 * b + 0] = acc0[b];
            sred[wave][2 * b + 1] = acc1[b];
        }
    }
    __syncthreads();
    if (threadIdx.x < 16) {
        float s = sred[0][threadIdx.x] + sred[1][threadIdx.x] +
                  sred[2][threadIdx.x] + sred[3][threadIdx.x];
        atomicAdd(&out[threadIdx.x], s);
    }
}

extern "C" void kernel_launch(void* const* d_in, const int* in_sizes, int n_in,
                              void* d_out, int out_size, void* d_ws, size_t ws_size,
                              hipStream_t stream) {
    const float* imgs = (const float*)d_in[0];
    const float* z    = (const float*)d_in[1];
    float* out        = (float*)d_out;
    int npts = in_sizes[1] / 2;

    size_t ws_need = (size_t)NPIX * 64;          // 64 MB T table

    if (ws_size < ws_need) {
        int blocks = (npts + 255) / 256;
        zero_out_kernel<<<1, 64, 0, stream>>>(out);
        interp_grad_kernel<<<blocks, 256, 0, stream>>>(imgs, z, out, npts);
        return;
    }

    uint4* T = (uint4*)d_ws;

    precompute_kernel<<<(NYX / 2) * 4, 256, 0, stream>>>(imgs, T, out);
    gather_kernel<<<GB, 256, 0, stream>>>(z, T, out, npts);
}

// Round 4
// 189.022 us; speedup vs baseline: 1.0177x; 1.0177x over previous
//
#include <hip/hip_runtime.h>
#include <hip/hip_fp16.h>

// imgs (8,3,1024,1024) fp32, z (1e6,2) fp32 -> out (8,2) fp32.
// R15 (this round):
//  - precompute: ROWS=2 kept (18 upfront float4 loads, 2048 blocks, 1.5x
//    read dedup) but the R14 barrier tax removed: compute BOTH rows' records
//    into registers (48 VGPRs) before staging, so sS and stage can share one
//    24.7 KB LDS union -> full 16 KB stage, 5 barriers/block (was 9).
//  - sS stride 256 (conflict-free for float4 writes and scalar reads); the
//    +1 edge column lives in sEdge[24] inside the union (was SROW=260 pad).
//  - fp32 S precision unchanged. XCD swizzle kept. out zeroed by block 0.
//  - gather + fused atomic reduce byte-identical to R13/R14.
// T record per pixel: 64 B = uint4[4]: [0]=Dy(8 half), [1]=Dx, [2]=M,
// [3]=pad -> exactly one cache line per gathered point.

#define NYX 1024
#define NPIX (NYX * NYX)
#define BATCH 8
#define CH 3
#define GB 1024                                  // gather blocks
#define SW(i) ((i) ^ (((i) >> 4) & 7))           // stage swizzle (involution)
#define EDGEI 6144                               // sEdge float index (24576 B)

__device__ __forceinline__ unsigned pk2(float a, float b) {
    __half2 h = __floats2half2_rn(a, b);
    return *(unsigned*)&h;
}

__device__ __forceinline__ float4 add4(float4 a, float4 b, float4 c) {
    return make_float4(a.x + b.x + c.x, a.y + b.y + c.y,
                       a.z + b.z + c.z, a.w + b.w + c.w);
}

__global__ __launch_bounds__(256, 4) void precompute_kernel(
    const float* __restrict__ imgs, uint4* __restrict__ T,
    float* __restrict__ out)
{
    // 2048 blocks. XCD swizzle: chunk of 256 logical blocks per XCD,
    // y-major within a strip so adjacent y-groups (sharing boundary row
    // y0+2) are dispatched back-to-back on the same XCD.
    int bid0  = blockIdx.x;
    int L     = ((bid0 & 7) << 8) | (bid0 >> 3); // bijective on [0,2048)
    int ygrp  = L & 511;
    int strip = L >> 9;                          // 0..3
    int y0    = ygrp << 1;
    int x0    = strip << 8;
    int t     = threadIdx.x;
    int lane  = t & 63;
    int g     = t >> 6;                          // group -> batches 2g,2g+1
    int xe    = min(x0 + 256, NYX - 1);          // strip-edge col

    if (bid0 == 0 && t < 16) out[t] = 0.0f;      // zero for gather's atomics

    // union: phase 1 = sS (24 rows x 256 f32 = 24576 B) + sEdge (24 f32);
    //        phase 2 = stage (1024 x uint4 = 16384 B). 24704 B total.
    __shared__ __align__(16) char smem[24704];
    float* sS    = (float*)smem;                 // row rr=b*3+r, col 0..255
    float* sEdge = (float*)smem + EDGEI;         // [rr] = col-256 value
    uint4* stage = (uint4*)smem;

    int yr0 = y0;
    int yr1 = min(y0 + 1, NYX - 1);
    int yr2 = min(y0 + 2, NYX - 1);              // row 1023 records unread
    size_t q[3] = { (size_t)yr0 * NYX + x0,
                    (size_t)yr1 * NYX + x0,
                    (size_t)yr2 * NYX + x0 };

    // 18 independent float4 loads (3 rows x 2 batches x 3 channels)
    float4 v[18];
#pragma unroll
    for (int r = 0; r < 3; ++r) {
#pragma unroll
        for (int bl = 0; bl < 2; ++bl) {
#pragma unroll
            for (int c = 0; c < CH; ++c) {
                const float* pl = imgs + (size_t)((2 * g + bl) * CH + c) * NPIX;
                v[r * 6 + bl * 3 + c] = ((const float4*)(pl + q[r]))[lane];
            }
        }
    }
    float edge[6] = {0.f, 0.f, 0.f, 0.f, 0.f, 0.f};
    if (lane == 63) {
        size_t qe[3] = { (size_t)yr0 * NYX + xe,
                         (size_t)yr1 * NYX + xe,
                         (size_t)yr2 * NYX + xe };
#pragma unroll
        for (int r = 0; r < 3; ++r) {
#pragma unroll
            for (int bl = 0; bl < 2; ++bl) {
#pragma unroll
                for (int c = 0; c < CH; ++c) {
                    const float* pl = imgs + (size_t)((2 * g + bl) * CH + c) * NPIX;
                    edge[r * 2 + bl] += pl[qe[r]];
                }
            }
        }
    }

    // channel-sum -> 3 S rows per batch (stride-256: f4 writes conflict-free)
#pragma unroll
    for (int r = 0; r < 3; ++r) {
#pragma unroll
        for (int bl = 0; bl < 2; ++bl) {
            int b = 2 * g + bl;
            float4 s = add4(v[r * 6 + bl * 3 + 0], v[r * 6 + bl * 3 + 1],
                            v[r * 6 + bl * 3 + 2]);
            *(float4*)&sS[(b * 3 + r) * 256 + 4 * lane] = s;
            if (lane == 63) sEdge[b * 3 + r] = edge[r * 2 + bl];
        }
    }
    __syncthreads();                             // B1: sS ready

    // records for BOTH rows into registers (48 VGPRs), then sS is dead
    float Dy[2][BATCH], Dx[2][BATCH], Mm[2][BATCH];
#pragma unroll
    for (int b = 0; b < BATCH; ++b) {
        float s[3], sp[3];
#pragma unroll
        for (int r = 0; r < 3; ++r) {
            int rr = b * 3 + r;
            s[r]  = sS[rr * 256 + t];
            sp[r] = sS[(t < 255) ? (rr * 256 + t + 1) : (EDGEI + rr)];
        }
        Dy[0][b] = s[1] - s[0];
        Dx[0][b] = sp[0] - s[0];
        Mm[0][b] = (sp[1] - sp[0]) - Dy[0][b];
        Dy[1][b] = s[2] - s[1];
        Dx[1][b] = sp[1] - s[1];
        Mm[1][b] = (sp[2] - sp[1]) - Dy[1][b];
    }
    __syncthreads();                             // B2: sS reads done, reuse LDS

#pragma unroll
    for (int k = 0; k < 2; ++k) {
        stage[SW(t * 4 + 0)] =
            make_uint4(pk2(Dy[k][0], Dy[k][1]), pk2(Dy[k][2], Dy[k][3]),
                       pk2(Dy[k][4], Dy[k][5]), pk2(Dy[k][6], Dy[k][7]));
        stage[SW(t * 4 + 1)] =
            make_uint4(pk2(Dx[k][0], Dx[k][1]), pk2(Dx[k][2], Dx[k][3]),
                       pk2(Dx[k][4], Dx[k][5]), pk2(Dx[k][6], Dx[k][7]));
        stage[SW(t * 4 + 2)] =
            make_uint4(pk2(Mm[k][0], Mm[k][1]), pk2(Mm[k][2], Mm[k][3]),
                       pk2(Mm[k][4], Mm[k][5]), pk2(Mm[k][6], Mm[k][7]));
        stage[SW(t * 4 + 3)] = make_uint4(0u, 0u, 0u, 0u);
        __syncthreads();                         // stage ready

        // coalesced copy-out: 1024 consecutive uint4 (16 KB, full lines)
        size_t base4 = ((size_t)(y0 + k) * NYX + x0) * 4;
#pragma unroll
        for (int i = 0; i < 4; ++i)
            T[base4 + i * 256 + t] = stage[SW(i * 256 + t)];
        if (k == 0) __syncthreads();             // stage reuse for row 1
    }
}

struct PtSetup {
    const uint4* t4;
    float u, v, s;
};

__device__ __forceinline__ PtSetup setup_pt(float zy, float zx,
                                            const uint4* __restrict__ T) {
    PtSetup r;
    float x0y = zy * (float)(NYX - 1);
    float x0x = zx * (float)(NYX - 1);
    bool oob = (x0y < 0.0f) || (x0y > (float)(NYX - 1)) ||
               (x0x < 0.0f) || (x0x > (float)(NYX - 1));
    float cy = fminf(fmaxf(x0y, 0.0f), (float)(NYX - 1));
    float cx = fminf(fmaxf(x0x, 0.0f), (float)(NYX - 1));
    int yg = min((int)cy, NYX - 2);
    int xg = min((int)cx, NYX - 2);
    r.u = cx - (float)xg;
    r.v = cy - (float)yg;
    r.s = oob ? 0.0f : 1.0f;
    r.t4 = T + ((size_t)yg * NYX + xg) * 4;
    return r;
}

__device__ __forceinline__ void accum_pt(PtSetup P, uint4 rDy, uint4 rDx,
                                         uint4 rM, float* acc0, float* acc1) {
    const __half2* hDy = (const __half2*)&rDy;
    const __half2* hDx = (const __half2*)&rDx;
    const __half2* hM  = (const __half2*)&rM;
#pragma unroll
    for (int j = 0; j < 4; ++j) {
        float2 dy = __half22float2(hDy[j]);
        float2 dx = __half22float2(hDx[j]);
        float2 m  = __half22float2(hM[j]);
        acc0[2 * j + 0] += P.s * fmaf(P.u, m.x, dy.x);
        acc0[2 * j + 1] += P.s * fmaf(P.u, m.y, dy.y);
        acc1[2 * j + 0] += P.s * fmaf(P.v, m.x, dx.x);
        acc1[2 * j + 1] += P.s * fmaf(P.v, m.y, dx.y);
    }
}

__global__ __launch_bounds__(256, 4) void gather_kernel(
    const float* __restrict__ z, const uint4* __restrict__ T,
    float* __restrict__ out, int npts)
{
    float acc0[BATCH];
    float acc1[BATCH];
#pragma unroll
    for (int b = 0; b < BATCH; ++b) { acc0[b] = 0.0f; acc1[b] = 0.0f; }

    const float4* z4 = (const float4*)z;
    int npairs = npts >> 1;
    int stride = gridDim.x * blockDim.x;
    int tid = blockIdx.x * blockDim.x + threadIdx.x;

    // 2 pairs (4 points) per iteration: 2 z-loads + 12 record loads in flight
    for (int i = tid; i < npairs; i += 2 * stride) {
        int i2 = i + stride;
        bool has2 = i2 < npairs;
        float4 za = z4[i];
        float4 zb = z4[has2 ? i2 : i];           // clamped dup, zeroed below
        PtSetup A = setup_pt(za.x, za.y, T);
        PtSetup B = setup_pt(za.z, za.w, T);
        PtSetup C = setup_pt(zb.x, zb.y, T);
        PtSetup D = setup_pt(zb.z, zb.w, T);
        if (!has2) { C.s = 0.0f; D.s = 0.0f; }
        uint4 aDy = A.t4[0], aDx = A.t4[1], aM = A.t4[2];
        uint4 bDy = B.t4[0], bDx = B.t4[1], bM = B.t4[2];
        uint4 cDy = C.t4[0], cDx = C.t4[1], cM = C.t4[2];
        uint4 dDy = D.t4[0], dDx = D.t4[1], dM = D.t4[2];
        accum_pt(A, aDy, aDx, aM, acc0, acc1);
        accum_pt(B, bDy, bDx, bM, acc0, acc1);
        accum_pt(C, cDy, cDx, cM, acc0, acc1);
        accum_pt(D, dDy, dDx, dM, acc0, acc1);
    }

    // odd-npts tail (not taken for npts = 1e6)
    if ((npts & 1) && blockIdx.x == 0 && threadIdx.x == 0) {
        float zy = z[2 * (npts - 1)], zx = z[2 * (npts - 1) + 1];
        PtSetup A = setup_pt(zy, zx, T);
        uint4 aDy = A.t4[0], aDx = A.t4[1], aM = A.t4[2];
        accum_pt(A, aDy, aDx, aM, acc0, acc1);
    }

#pragma unroll
    for (int b = 0; b < BATCH; ++b) {
#pragma unroll
        for (int off = 32; off > 0; off >>= 1) {
            acc0[b] += __shfl_down(acc0[b], off, 64);
            acc1[b] += __shfl_down(acc1[b], off, 64);
        }
    }

    __shared__ float sred[4][16];
    int lane = threadIdx.x & 63;
    int wave = threadIdx.x >> 6;
    if (lane == 0) {
#pragma unroll
        for (int b = 0; b < BATCH; ++b) {
            sred[wave][2 * b + 0] = acc0[b];
            sred[wave][2 * b + 1] = acc1[b];
        }
    }
    __syncthreads();
    if (threadIdx.x < 16) {
        float s = sred[0][threadIdx.x] + sred[1][threadIdx.x] +
                  sred[2][threadIdx.x] + sred[3][threadIdx.x];
        atomicAdd(&out[threadIdx.x], s);         // out zeroed by precompute
    }
}

// ---- fallback (round-1 unsorted path) if ws is too small ----
__global__ void zero_out_kernel(float* __restrict__ out) {
    int i = threadIdx.x;
    if (i < 16) out[i] = 0.0f;
}

__global__ __launch_bounds__(256) void interp_grad_kernel(
    const float* __restrict__ imgs, const float* __restrict__ z,
    float* __restrict__ out, int npts)
{
    int p = blockIdx.x * blockDim.x + threadIdx.x;
    float acc0[BATCH];
    float acc1[BATCH];
#pragma unroll
    for (int b = 0; b < BATCH; ++b) { acc0[b] = 0.0f; acc1[b] = 0.0f; }
    if (p < npts) {
        float2 zz = ((const float2*)z)[p];
        float x0y = zz.x * (float)(NYX - 1);
        float x0x = zz.y * (float)(NYX - 1);
        bool oob = (x0y < 0.0f) || (x0y > (float)(NYX - 1)) ||
                   (x0x < 0.0f) || (x0x > (float)(NYX - 1));
        if (!oob) {
            int yg = min((int)floorf(x0y), NYX - 2);
            int xg = min((int)floorf(x0x), NYX - 2);
            float fy = (float)yg - x0y;
            float fx = (float)xg - x0x;
            const float* base = imgs + (size_t)yg * NYX + xg;
#pragma unroll
            for (int b = 0; b < BATCH; ++b) {
#pragma unroll
                for (int c = 0; c < CH; ++c) {
                    const float* pl = base + (size_t)(b * CH + c) * (size_t)NPIX;
                    float g00 = pl[0];
                    float g01 = pl[1];
                    float g10 = pl[NYX];
                    float g11 = pl[NYX + 1];
                    float a1 = g10 - g00;
                    float a2 = g11 - g01;
                    float a3 = g01 - g00;
                    float d  = a1 - a2;
                    acc0[b] += d * fx + a1;
                    acc1[b] += d * fy + a3;
                }
            }
        }
    }
#pragma unroll
    for (int b = 0; b < BATCH; ++b) {
#pragma unroll
        for (int off = 32; off > 0; off >>= 1) {
            acc0[b] += __shfl_down(acc0[b], off, 64);
            acc1[b] += __shfl_down(acc1[b], off, 64);
        }
    }
    __shared__ float sred[4][16];
    int lane = threadIdx.x & 63;
    int wave = threadIdx.x >> 6;
    if (lane == 0) {
#pragma unroll
        for (int b = 0; b < BATCH; ++b) {
            sred[wave][2 * b + 0] = acc0[b];
            sred[wave][2 * b + 1] = acc1[b];
        }
    }
    __syncthreads();
    if (threadIdx.x < 16) {
        float s = sred[0][threadIdx.x] + sred[1][threadIdx.x] +
                  sred[2][threadIdx.x] + sred[3][threadIdx.x];
        atomicAdd(&out[threadIdx.x], s);
    }
}

extern "C" void kernel_launch(void* const* d_in, const int* in_sizes, int n_in,
                              void* d_out, int out_size, void* d_ws, size_t ws_size,
                              hipStream_t stream) {
    const float* imgs = (const float*)d_in[0];
    const float* z    = (const float*)d_in[1];
    float* out        = (float*)d_out;
    int npts = in_sizes[1] / 2;

    size_t ws_need = (size_t)NPIX * 64;          // 64 MB T table

    if (ws_size < ws_need) {
        int blocks = (npts + 255) / 256;
        zero_out_kernel<<<1, 64, 0, stream>>>(out);
        interp_grad_kernel<<<blocks, 256, 0, stream>>>(imgs, z, out, npts);
        return;
    }

    uint4* T = (uint4*)d_ws;

    precompute_kernel<<<(NYX / 2) * 4, 256, 0, stream>>>(imgs, T, out);
    gather_kernel<<<GB, 256, 0, stream>>>(z, T, out, npts);
}